// Round 1
// 21267.125 us; speedup vs baseline: 5.3273x; 5.3273x over previous
//
#include <hip/hip_runtime.h>
#include <hip/hip_bf16.h>

typedef __hip_bfloat16 bf16;
using bf16x8 = __attribute__((ext_vector_type(8))) short;   // 8 bf16 = 4 VGPRs
using f32x4  = __attribute__((ext_vector_type(4))) float;   // MFMA accumulator

#define B_   256
#define T1_  128
#define S_   128
#define A_   32
#define H_   1024
#define E_   1024
#define MIN_STD 0.1f

// ---- dtype-flexible load/store: isbf resolved at runtime from device probe ----
__device__ __forceinline__ float loadT(const void* p, int isbf, long idx) {
  return isbf ? __bfloat162float(((const bf16*)p)[idx]) : ((const float*)p)[idx];
}
__device__ __forceinline__ void storeT(void* p, int isbf, long idx, float v) {
  if (isbf) ((bf16*)p)[idx] = __float2bfloat16(v);
  else      ((float*)p)[idx] = v;
}

// Probe: read nelem elements of a weight tensor (values ~N(0, 1/32)) AS bf16.
// f32 data read as bf16 -> garbage exponents / NaN. flag=1 => input is bf16.
__global__ void dtype_probe(const void* __restrict__ p, int nelem, int* __restrict__ flag) {
  __shared__ int bad;
  if (threadIdx.x == 0) bad = 0;
  __syncthreads();
  const bf16* q = (const bf16*)p;
  int lbad = 0;
  for (int i = threadIdx.x; i < nelem; i += 256) {
    float v = __bfloat162float(q[i]);
    if (!(fabsf(v) <= 1e6f)) lbad = 1;
  }
  if (lbad) atomicOr(&bad, 1);
  __syncthreads();
  if (threadIdx.x == 0) *flag = bad ? 0 : 1;
}

// Split any tensor (dtype via flag) into hi/lo bf16 planes: v ~= h + l, err <= 2^-16|v|.
__global__ __launch_bounds__(256)
void split_plane(const void* __restrict__ src, long n, bf16* __restrict__ h,
                 bf16* __restrict__ l, const int* __restrict__ flagp) {
  const int F = *flagp;
  long i = (long)blockIdx.x * 256 + threadIdx.x;
  if (i < n) {
    float v = loadT(src, F, i);
    bf16 hv = __float2bfloat16(v);
    h[i] = hv;
    l[i] = __float2bfloat16(v - __bfloat162float(hv));
  }
}

// ---------------- MFMA GEMM: C = act(A @ W^T + bias) ----------------
// A operand = split bf16 planes (hi/lo), optionally concat of two segments
// (k < K1 from A planes, k >= K1 from A2 planes at aoff2). W = split planes.
// Out: fp32 (Cf) and/or split bf16 planes (Ch/Cl). M=256 always, N%64==0,
// K1%32==0, K%32==0. Grid = (N/64)*(M/64) blocks per problem; up to 3
// problems fused per launch. 256 thr = 4 waves; wave w owns 32x32 quadrant,
// 2x2 fragments of 16x16x32 MFMA. 3 MFMAs/fragment give ~fp32 precision:
// acc += Ah*Wh + Al*Wh + Ah*Wl  (dropped Al*Wl term is O(2^-16)).
struct GProb {
  const bf16 *Ah, *Al; int lda;
  const bf16 *A2h, *A2l; int lda2; int K1; long aoff2;
  const bf16 *Wh, *Wl; int ldw;
  const void* bias;
  float* Cf; bf16 *Ch, *Cl; int ldc;
  int relu; int nbx; int K;
};

__device__ __forceinline__ void gemm_seg(f32x4 (&acc)[2][2],
    const bf16* __restrict__ ah, const bf16* __restrict__ al, int lda, long abase,
    int ks, int ke,
    const bf16* __restrict__ wh, const bf16* __restrict__ wl, int ldw,
    int r0, int c0, int lk)
{
  #pragma unroll 2
  for (int kt = ks; kt < ke; kt += 32) {
    bf16x8 fa_h[2], fa_l[2], fw_h[2], fw_l[2];
    #pragma unroll
    for (int i = 0; i < 2; ++i) {
      long ao = (long)(r0 + i * 16) * lda + abase + (kt - ks) + lk;
      fa_h[i] = *(const bf16x8*)(ah + ao);
      fa_l[i] = *(const bf16x8*)(al + ao);
      long wo = (long)(c0 + i * 16) * ldw + kt + lk;
      fw_h[i] = *(const bf16x8*)(wh + wo);
      fw_l[i] = *(const bf16x8*)(wl + wo);
    }
    #pragma unroll
    for (int i = 0; i < 2; ++i)
      #pragma unroll
      for (int j = 0; j < 2; ++j) {
        acc[i][j] = __builtin_amdgcn_mfma_f32_16x16x32_bf16(fa_h[i], fw_h[j], acc[i][j], 0, 0, 0);
        acc[i][j] = __builtin_amdgcn_mfma_f32_16x16x32_bf16(fa_l[i], fw_h[j], acc[i][j], 0, 0, 0);
        acc[i][j] = __builtin_amdgcn_mfma_f32_16x16x32_bf16(fa_h[i], fw_l[j], acc[i][j], 0, 0, 0);
      }
  }
}

__global__ __launch_bounds__(256)
void mfma_gemm(GProb p0, GProb p1, GProb p2, int n0, int n01,
               const int* __restrict__ flagp)
{
  int blk = blockIdx.x;
  GProb p;
  if (blk < n0) p = p0;
  else if (blk < n01) { blk -= n0; p = p1; }
  else { blk -= n01; p = p2; }
  const int F = *flagp;

  const int bx   = blk % p.nbx;
  const int by   = blk / p.nbx;
  const int m0   = by * 64;
  const int nc0  = bx * 64;
  const int w    = threadIdx.x >> 6;
  const int lane = threadIdx.x & 63;
  const int wm   = (w >> 1) * 32;
  const int wn   = (w & 1) * 32;
  const int lr   = lane & 15;
  const int lk   = (lane >> 4) * 8;

  const int r0 = m0 + wm + lr;    // A row, fragment i adds +16*i
  const int c0 = nc0 + wn + lr;   // W row (output col), fragment j adds +16*j

  f32x4 zz = {0.f, 0.f, 0.f, 0.f};
  f32x4 acc[2][2] = {{zz, zz}, {zz, zz}};

  gemm_seg(acc, p.Ah, p.Al, p.lda, 0, 0, p.K1, p.Wh, p.Wl, p.ldw, r0, c0, lk);
  if (p.K1 < p.K)
    gemm_seg(acc, p.A2h, p.A2l, p.lda2, p.aoff2, p.K1, p.K, p.Wh, p.Wl, p.ldw, r0, c0, lk);

  // C/D layout (m89-verified): col = lane&15, row = (lane>>4)*4 + reg
  float bv0 = loadT(p.bias, F, c0);
  float bv1 = loadT(p.bias, F, c0 + 16);
  const int rb = m0 + wm + ((lane >> 4) << 2);
  #pragma unroll
  for (int i = 0; i < 2; ++i) {
    #pragma unroll
    for (int j = 0; j < 2; ++j) {
      const int n  = c0 + j * 16;
      const float bv = j ? bv1 : bv0;
      #pragma unroll
      for (int r = 0; r < 4; ++r) {
        float v = acc[i][j][r] + bv;
        if (p.relu) v = fmaxf(v, 0.f);
        long o = (long)(rb + i * 16 + r) * p.ldc + n;
        if (p.Cf) p.Cf[o] = v;
        if (p.Ch) {
          bf16 hv = __float2bfloat16(v);
          p.Ch[o] = hv;
          p.Cl[o] = __float2bfloat16(v - __bfloat162float(hv));
        }
      }
    }
  }
}

// GRU elementwise + split-write of b1 + split of Obs[:, t] (same index space).
__global__ __launch_bounds__(256)
void gru_ew(const float* __restrict__ gi, const float* __restrict__ gh,
            const void* __restrict__ hprev, int hm,
            void* __restrict__ out, int t, float* __restrict__ b_f,
            bf16* __restrict__ bh, bf16* __restrict__ bl,
            const void* __restrict__ Obs, bf16* __restrict__ oh,
            bf16* __restrict__ ol, const int* __restrict__ flagp)
{
  const int F = *flagp;
  const int fh = hm & F;
  int tid = blockIdx.x * 256 + threadIdx.x;   // 0 .. B*H-1
  int b = tid >> 10;
  int j = tid & 1023;
  long gbase = (long)b * 3072;
  float ir  = gi[gbase + j],        hr = gh[gbase + j];
  float iz  = gi[gbase + 1024 + j], hz = gh[gbase + 1024 + j];
  float in_ = gi[gbase + 2048 + j], hn = gh[gbase + 2048 + j];
  float h = loadT(hprev, fh, (long)b * H_ + j);
  float r = 1.f / (1.f + expf(-(ir + hr)));
  float z = 1.f / (1.f + expf(-(iz + hz)));
  float n = tanhf(in_ + r * hn);
  float v = (1.f - z) * n + z * h;
  storeT(out, F, (long)b * (T1_ * H_) + (long)t * H_ + j, v);
  b_f[tid] = v;
  bf16 vh = __float2bfloat16(v);
  bh[tid] = vh;
  bl[tid] = __float2bfloat16(v - __bfloat162float(vh));
  // split this step's Observation slice for the hq GEMM (next launch)
  float ov = loadT(Obs, F, (long)b * (T1_ * E_) + (long)t * E_ + j);
  bf16 ovh = __float2bfloat16(ov);
  oh[tid] = ovh;
  ol[tid] = __float2bfloat16(ov - __bfloat162float(ovh));
}

__device__ __forceinline__ float softplusf_(float x) {
  return fmaxf(x, 0.f) + log1pf(expf(-fabsf(x)));
}

// Sampling epilogue: outputs + split-write of s_q carry for next x-GEMM.
__global__ __launch_bounds__(256)
void sample_ew(const float* __restrict__ catp, const float* __restrict__ catq,
               const void* __restrict__ npri, const void* __restrict__ npos,
               void* __restrict__ out, int t,
               bf16* __restrict__ sh, bf16* __restrict__ sl,
               const int* __restrict__ flagp)
{
  const int F = *flagp;
  int tid = blockIdx.x * 256 + threadIdx.x;   // 0 .. B*S-1
  int b = tid >> 7;
  int s = tid & 127;
  const long SZH = (long)B_ * T1_ * H_;
  const long SZS = (long)B_ * T1_ * S_;
  long nidx = (long)b * (T1_ * S_) + (long)t * S_ + s;
  long crow = (long)b * 256;
  float mu_p = catp[crow + s];
  float h2p  = catp[crow + 128 + s];
  float mu_q = catq[crow + s];
  float h2q  = catq[crow + 128 + s];
  float std_p = softplusf_(h2p) + MIN_STD;
  float std_q = softplusf_(h2q) + MIN_STD;
  float s_p = mu_p + std_p * loadT(npri, F, nidx);
  float s_q = mu_q + std_q * loadT(npos, F, nidx);
  storeT(out, F, SZH + 0 * SZS + nidx, s_p);
  storeT(out, F, SZH + 1 * SZS + nidx, mu_p);
  storeT(out, F, SZH + 2 * SZS + nidx, std_p);
  storeT(out, F, SZH + 3 * SZS + nidx, s_q);
  storeT(out, F, SZH + 4 * SZS + nidx, mu_q);
  storeT(out, F, SZH + 5 * SZS + nidx, std_q);
  bf16 qh = __float2bfloat16(s_q);
  sh[tid] = qh;
  sl[tid] = __float2bfloat16(s_q - __bfloat162float(qh));
}

extern "C" void kernel_launch(void* const* d_in, const int* in_sizes, int n_in,
                              void* d_out, int out_size, void* d_ws, size_t ws_size,
                              hipStream_t stream) {
  const void* s0     = d_in[0];
  const void* b0     = d_in[1];
  const void* Act    = d_in[2];
  const void* Obs    = d_in[3];
  const void* npri   = d_in[4];
  const void* npos   = d_in[5];
  const void* W_sa   = d_in[6];
  const void* b_sa   = d_in[7];
  const void* W_ih   = d_in[8];
  const void* W_hh   = d_in[9];
  const void* b_ih   = d_in[10];
  const void* b_hh   = d_in[11];
  const void* W_bpri = d_in[12];
  const void* b_bpri = d_in[13];
  const void* W_spri = d_in[14];
  const void* b_spri = d_in[15];
  const void* W_bpos = d_in[16];
  const void* b_bpos = d_in[17];
  const void* W_spos = d_in[18];
  const void* b_spos = d_in[19];
  (void)in_sizes; (void)n_in; (void)out_size; (void)ws_size;

  // ---- workspace carve (~58 MB total; all buffers 256B aligned) ----
  char* base = (char*)d_ws;
  size_t off = 0;
  auto carve = [&](size_t bytes) {
    void* p = base + off;
    off = (off + bytes + 255) & ~(size_t)255;
    return p;
  };
  float* gi_f   = (float*)carve(sizeof(float) * B_ * 3 * H_);
  float* gh_f   = (float*)carve(sizeof(float) * B_ * 3 * H_);
  float* b_f    = (float*)carve(sizeof(float) * B_ * H_);
  float* catp_f = (float*)carve(sizeof(float) * B_ * 2 * S_);
  float* catq_f = (float*)carve(sizeof(float) * B_ * 2 * S_);
  int*   flagp  = (int*)carve(256);
  auto plane = [&](size_t n) { return (bf16*)carve(2 * n); };
  bf16 *xh = plane((size_t)B_ * H_),  *xl = plane((size_t)B_ * H_);
  bf16 *bh = plane((size_t)B_ * H_),  *bl = plane((size_t)B_ * H_);
  bf16 *hph = plane((size_t)B_ * H_), *hpl = plane((size_t)B_ * H_);
  bf16 *hqh = plane((size_t)B_ * H_), *hql = plane((size_t)B_ * H_);
  bf16 *sh = plane((size_t)B_ * S_),  *sl = plane((size_t)B_ * S_);
  bf16 *oh = plane((size_t)B_ * E_),  *ol = plane((size_t)B_ * E_);
  bf16 *acth = plane((size_t)B_ * T1_ * A_), *actl = plane((size_t)B_ * T1_ * A_);
  bf16 *wsah  = plane((size_t)H_ * (S_ + A_)), *wsal  = plane((size_t)H_ * (S_ + A_));
  bf16 *wihh  = plane((size_t)3 * H_ * H_),    *wihl  = plane((size_t)3 * H_ * H_);
  bf16 *whhh  = plane((size_t)3 * H_ * H_),    *whhl  = plane((size_t)3 * H_ * H_);
  bf16 *wprih = plane((size_t)H_ * H_),        *wpril = plane((size_t)H_ * H_);
  bf16 *wsprih = plane((size_t)2 * S_ * H_),   *wspril = plane((size_t)2 * S_ * H_);
  bf16 *wposh = plane((size_t)H_ * (H_ + E_)), *wposl = plane((size_t)H_ * (H_ + E_));
  bf16 *wsposh = plane((size_t)2 * S_ * H_),   *wsposl = plane((size_t)2 * S_ * H_);

  dim3 blk(256);

  // ---- setup: dtype probe, weight/input splits, gh_0 ----
  dtype_probe<<<dim3(1), blk, 0, stream>>>(W_ih, 8192, flagp);
  auto split = [&](const void* src, size_t n, bf16* h, bf16* l) {
    split_plane<<<dim3((unsigned)((n + 255) / 256)), blk, 0, stream>>>(src, (long)n, h, l, flagp);
  };
  split(W_sa,   (size_t)H_ * (S_ + A_), wsah, wsal);
  split(W_ih,   (size_t)3 * H_ * H_,    wihh, wihl);
  split(W_hh,   (size_t)3 * H_ * H_,    whhh, whhl);
  split(W_bpri, (size_t)H_ * H_,        wprih, wpril);
  split(W_spri, (size_t)2 * S_ * H_,    wsprih, wspril);
  split(W_bpos, (size_t)H_ * (H_ + E_), wposh, wposl);
  split(W_spos, (size_t)2 * S_ * H_,    wsposh, wsposl);
  split(s0,  (size_t)B_ * S_,        sh, sl);
  split(b0,  (size_t)B_ * H_,        bh, bl);
  split(Act, (size_t)B_ * T1_ * A_,  acth, actl);

  auto mk = [](const bf16* Ah, const bf16* Al, int lda,
               const bf16* A2h, const bf16* A2l, int lda2, int K1, long aoff2,
               const bf16* Wh, const bf16* Wl, int ldw, const void* bias,
               float* Cf, bf16* Ch, bf16* Cl, int ldc, int relu, int N, int K) {
    GProb p;
    p.Ah = Ah; p.Al = Al; p.lda = lda;
    p.A2h = A2h; p.A2l = A2l; p.lda2 = lda2; p.K1 = K1; p.aoff2 = aoff2;
    p.Wh = Wh; p.Wl = Wl; p.ldw = ldw; p.bias = bias;
    p.Cf = Cf; p.Ch = Ch; p.Cl = Cl; p.ldc = ldc;
    p.relu = relu; p.nbx = N / 64; p.K = K;
    return p;
  };

  // problem descriptors (t-invariant except Px.aoff2)
  GProb Pgh = mk(bh, bl, H_,  bh, bl, H_, H_, 0,  whhh, whhl, H_, b_hh,
                 gh_f, nullptr, nullptr, 3 * H_, 0, 3 * H_, H_);          // 192 blocks
  GProb Pgi = mk(xh, xl, H_,  xh, xl, H_, H_, 0,  wihh, wihl, H_, b_ih,
                 gi_f, nullptr, nullptr, 3 * H_, 0, 3 * H_, H_);          // 192 blocks
  GProb Px  = mk(sh, sl, S_,  acth, actl, T1_ * A_, S_, 0, wsah, wsal, S_ + A_, b_sa,
                 nullptr, xh, xl, H_, 1, H_, S_ + A_);                    // 64 blocks
  GProb Php = mk(bh, bl, H_,  bh, bl, H_, H_, 0,  wprih, wpril, H_, b_bpri,
                 nullptr, hph, hpl, H_, 1, H_, H_);                       // 64 blocks
  GProb Phq = mk(bh, bl, H_,  oh, ol, E_, H_, 0,  wposh, wposl, H_ + E_, b_bpos,
                 nullptr, hqh, hql, H_, 1, H_, H_ + E_);                  // 64 blocks
  GProb Pcp = mk(hph, hpl, H_, hph, hpl, H_, H_, 0, wsprih, wspril, H_, b_spri,
                 catp_f, nullptr, nullptr, 2 * S_, 0, 2 * S_, H_);        // 16 blocks
  GProb Pcq = mk(hqh, hql, H_, hqh, hql, H_, H_, 0, wsposh, wsposl, H_, b_spos,
                 catq_f, nullptr, nullptr, 2 * S_, 0, 2 * S_, H_);        // 16 blocks

  // gh_0 = b0 @ W_hh^T + b_hh (from b0 split planes)
  mfma_gemm<<<dim3(192), blk, 0, stream>>>(Pgh, Pgh, Pgh, 192, 192, flagp);

  for (int t = 0; t < T1_; ++t) {
    // x_t = relu([s_{t-1}, a_t] @ W_sa^T + b_sa)
    Px.aoff2 = (long)t * A_;
    mfma_gemm<<<dim3(64), blk, 0, stream>>>(Px, Px, Px, 64, 64, flagp);
    // gi_t = x_t @ W_ih^T + b_ih
    mfma_gemm<<<dim3(192), blk, 0, stream>>>(Pgi, Pgi, Pgi, 192, 192, flagp);
    // GRU elementwise -> b1 (y0, f32 carry, split planes) + split Obs_t
    gru_ew<<<dim3(B_ * H_ / 256), blk, 0, stream>>>(
        gi_f, gh_f, t ? (const void*)b_f : b0, t ? 0 : 1,
        d_out, t, b_f, bh, bl, Obs, oh, ol, flagp);
    // hp_t | hq_t | gh_{t+1}  (gh for the NEXT step — only needs b1_t)
    mfma_gemm<<<dim3(64 + 64 + 192), blk, 0, stream>>>(Php, Phq, Pgh, 64, 128, flagp);
    // catp | catq
    mfma_gemm<<<dim3(32), blk, 0, stream>>>(Pcp, Pcq, Pcq, 16, 32, flagp);
    // sampling epilogue -> y1..y6 + split s_q carry
    sample_ew<<<dim3(B_ * S_ / 256), blk, 0, stream>>>(
        catp_f, catq_f, npri, npos, d_out, t, sh, sl, flagp);
  }
}